// Round 8
// baseline (533.289 us; speedup 1.0000x reference)
//
#include <hip/hip_runtime.h>
#include <cstdint>
#include <cstddef>

static constexpr int IN_DIM = 512;
static constexpr int HID = 128;
static constexpr int OUT_DIM = 64;

// CSR build params
static constexpr int BUKSH = 10;          // 1024 nodes per coarse bucket
static constexpr int MAXBUK = 128;        // >= nbuk = ceil(N/1024) = 98
static constexpr int BINCAP = 96;         // LDS bin capacity (avg fill ~42)
static constexpr int EPB = 4096;          // edges per block in phase 1
static constexpr int BCAP2 = 24576;       // ebuf capacity per bucket (avg 16.3k)

typedef __attribute__((ext_vector_type(8))) short bf16x8;
typedef __attribute__((ext_vector_type(4))) float f32x4;

__device__ inline unsigned short f2bf(float x) {
    unsigned u = __float_as_uint(x);
    unsigned r = (u + 0x7FFFu + ((u >> 16) & 1u)) >> 16;   // RNE
    return (unsigned short)r;
}
__device__ inline float bf2f(unsigned short b) { return __uint_as_float(((unsigned)b) << 16); }
__device__ inline float bflo(unsigned u) { return __uint_as_float(u << 16); }
__device__ inline float bfhi(unsigned u) { return __uint_as_float(u & 0xFFFF0000u); }

__device__ inline void gload_lds16(const void* g, void* l) {
    __builtin_amdgcn_global_load_lds(
        (const __attribute__((address_space(1))) unsigned int*)g,
        (__attribute__((address_space(3))) unsigned int*)(unsigned long long)(uintptr_t)l,
        16, 0, 0);
}

// ============ CSR construction: LDS-binned bucket sort (rebuilt every call) ============
// entry pack: src (bits 0-16) | (dst & 1023) << 17

__global__ __launch_bounds__(256) void k_bucket2(const int* __restrict__ src,
                                                 const int* __restrict__ dst, int E, int nbuk,
                                                 int* __restrict__ bcur,
                                                 unsigned* __restrict__ ebuf) {
    __shared__ int bincnt[MAXBUK];
    __shared__ int binbase[MAXBUK];
    __shared__ unsigned binbuf[MAXBUK][BINCAP];
    const int t = threadIdx.x;
    for (int i = t; i < MAXBUK; i += 256) bincnt[i] = 0;
    __syncthreads();

    const int e0 = blockIdx.x * EPB;
#pragma unroll
    for (int q = 0; q < EPB / 256; q++) {
        int e = e0 + q * 256 + t;
        if (e < E) {
            int s = src[e], d = dst[e];
            int b = d >> BUKSH;
            unsigned v = (unsigned)s | ((unsigned)(d & ((1 << BUKSH) - 1)) << 17);
            int pos = atomicAdd(&bincnt[b], 1);
            if (pos < BINCAP) {
                binbuf[b][pos] = v;
            } else {
                int p = atomicAdd(&bcur[b], 1);
                if (p < BCAP2) ebuf[(size_t)b * BCAP2 + p] = v;
            }
        }
    }
    __syncthreads();

    if (t < MAXBUK) {
        int c = (t < nbuk) ? min(bincnt[t], BINCAP) : 0;
        binbase[t] = c ? atomicAdd(&bcur[t], c) : 0;
        bincnt[t] = c;
    }
    __syncthreads();

    const int wave = t >> 6, lane = t & 63;
    for (int b = wave; b < nbuk; b += 4) {
        int c = bincnt[b];
        int base = binbase[b];
        int cc = min(c, max(0, BCAP2 - base));
        for (int i = lane; i < cc; i += 64)
            ebuf[(size_t)b * BCAP2 + base + i] = binbuf[b][i];
    }
}

__global__ __launch_bounds__(256) void k_hist2(const unsigned* __restrict__ ebuf,
                                               const int* __restrict__ bcur, int N,
                                               int* __restrict__ counts) {
    __shared__ int lcnt[1 << BUKSH];
    const int b = blockIdx.x, t = threadIdx.x;
    for (int i = t; i < (1 << BUKSH); i += 256) lcnt[i] = 0;
    __syncthreads();
    const int cnt = min(bcur[b], BCAP2);
    const unsigned* eb = ebuf + (size_t)b * BCAP2;
    for (int i = t; i < cnt; i += 256) atomicAdd(&lcnt[eb[i] >> 17], 1);
    __syncthreads();
    const int n0 = b << BUKSH;
    for (int i = t; i < (1 << BUKSH); i += 256)
        if (n0 + i < N) counts[n0 + i] = lcnt[i];
}

__global__ void k_scan1(const int* __restrict__ counts, int N, int* __restrict__ offs,
                        int* __restrict__ bsums) {
    __shared__ int sm[1024];
    int i = blockIdx.x * 1024 + threadIdx.x;
    int v = (i < N) ? counts[i] : 0;
    sm[threadIdx.x] = v;
    __syncthreads();
    for (int d = 1; d < 1024; d <<= 1) {
        int t = (threadIdx.x >= d) ? sm[threadIdx.x - d] : 0;
        __syncthreads();
        sm[threadIdx.x] += t;
        __syncthreads();
    }
    if (i < N) offs[i] = sm[threadIdx.x] - v;
    if (threadIdx.x == 1023) bsums[blockIdx.x] = sm[1023];
}

__global__ void k_scan2(int* __restrict__ bsums, int nb) {
    __shared__ int sm[256];
    int x = threadIdx.x;
    int v = (x < nb) ? bsums[x] : 0;
    sm[x] = v;
    __syncthreads();
    for (int d = 1; d < 256; d <<= 1) {
        int t = (x >= d) ? sm[x - d] : 0;
        __syncthreads();
        sm[x] += t;
        __syncthreads();
    }
    if (x < nb) bsums[x] = sm[x] - v;
}

__global__ void k_scan3(int* __restrict__ offs, const int* __restrict__ bsums, int N, int E) {
    int i = blockIdx.x * 1024 + threadIdx.x;
    if (i < N) offs[i] += bsums[blockIdx.x];
    if (blockIdx.x == 0 && threadIdx.x == 0) offs[N] = E;
}

__global__ void k_dinv(const int* __restrict__ counts, int N, float* __restrict__ dinv) {
    int i = blockIdx.x * blockDim.x + threadIdx.x;
    if (i < N) dinv[i] = rsqrtf((float)(counts[i] + 1));
}

__global__ __launch_bounds__(256) void k_csr2(const unsigned* __restrict__ ebuf,
                                              const int* __restrict__ bcur,
                                              const int* __restrict__ offs, int N,
                                              int* __restrict__ ssrc) {
    __shared__ int lcur[1 << BUKSH];
    const int b = blockIdx.x, t = threadIdx.x;
    const int n0 = b << BUKSH;
    for (int i = t; i < (1 << BUKSH); i += 256)
        lcur[i] = (n0 + i < N) ? offs[n0 + i] : 0;
    __syncthreads();
    const int cnt = min(bcur[b], BCAP2);
    const unsigned* eb = ebuf + (size_t)b * BCAP2;
    for (int i = t; i < cnt; i += 256) {
        unsigned v = eb[i];
        int p = atomicAdd(&lcur[v >> 17], 1);
        ssrc[p] = (int)(v & 0x1FFFFu);
    }
}

// ---------------- W pack: per-kg contiguous MFMA B-fragment blocks (hi/lo interleaved) -------

__global__ void k_packW(const float* __restrict__ W, int K, int M,
                        unsigned short* __restrict__ wpk) {
    int idx = blockIdx.x * 256 + threadIdx.x;
    int total = K * M * 2;
    if (idx >= total) return;
    int j = idx & 7;
    int l = (idx >> 3) & 63;
    int h = (idx >> 9) & 1;
    int rest = idx >> 10;
    int NF = M >> 4;
    int f = rest % NF;
    int kg = rest / NF;
    int k = kg * 32 + (l >> 4) * 8 + j;
    int col = f * 16 + (l & 15);
    float v = W[(size_t)k * M + col];
    unsigned short hi = f2bf(v);
    wpk[idx] = h ? f2bf(v - bf2f(hi)) : hi;
}

// ------- layer-1 GEMM: sliced-out C_bf16[f][N][16] = dinv ⊙ (A_f32[N,K] @ W[K,M]) -----

template <int K, int M>
__global__ __launch_bounds__(256) void k_gemm1(const float* __restrict__ A,
                                               const unsigned short* __restrict__ wpk,
                                               const float* __restrict__ dinv,
                                               unsigned short* __restrict__ Cout, int N) {
    constexpr int NF = M / 16;
    constexpr int KG = K / 32;
    constexpr int KGB = NF * 2 * 1024;
    constexpr int NISS = KGB / 4096;
    __shared__ unsigned char smem[2][KGB];

    const int wave = threadIdx.x >> 6;
    const int lane = threadIdx.x & 63;
    const int c = lane & 15, g = lane >> 4;
    const int r0 = blockIdx.x * 128 + wave * 32;

    f32x4 acc[2][NF];
#pragma unroll
    for (int m = 0; m < 2; m++)
#pragma unroll
        for (int f = 0; f < NF; f++) acc[m][f] = (f32x4){0.f, 0.f, 0.f, 0.f};

    const int rA0 = min(r0 + c, N - 1);
    const int rA1 = min(r0 + 16 + c, N - 1);
    const float* ap0 = A + (size_t)rA0 * K + g * 8;
    const float* ap1 = A + (size_t)rA1 * K + g * 8;

#define STAGE1(kg_, buf_)                                                              \
    {                                                                                  \
        _Pragma("unroll") for (int i = 0; i < NISS; ++i) {                             \
            const unsigned short* gsrc =                                               \
                wpk + (((size_t)(kg_)*KGB + (size_t)i * 4096 + (size_t)wave * 1024) >> 1) + \
                (size_t)lane * 8;                                                      \
            gload_lds16(gsrc, &smem[buf_][i * 4096 + wave * 1024]);                    \
        }                                                                              \
    }

    STAGE1(0, 0);
    float av0[8], av1[8];
    *(float4*)&av0[0] = *(const float4*)(ap0);
    *(float4*)&av0[4] = *(const float4*)(ap0 + 4);
    *(float4*)&av1[0] = *(const float4*)(ap1);
    *(float4*)&av1[4] = *(const float4*)(ap1 + 4);
    __syncthreads();

    int buf = 0;
    for (int kg = 0; kg < KG; ++kg) {
        if (kg + 1 < KG) STAGE1(kg + 1, buf ^ 1);
        float nv0[8], nv1[8];
        if (kg + 1 < KG) {
            *(float4*)&nv0[0] = *(const float4*)(ap0 + (kg + 1) * 32);
            *(float4*)&nv0[4] = *(const float4*)(ap0 + (kg + 1) * 32 + 4);
            *(float4*)&nv1[0] = *(const float4*)(ap1 + (kg + 1) * 32);
            *(float4*)&nv1[4] = *(const float4*)(ap1 + (kg + 1) * 32 + 4);
        }
        bf16x8 ah0, al0, ah1, al1;
#pragma unroll
        for (int j = 0; j < 8; ++j) {
            unsigned short h0 = f2bf(av0[j]);
            unsigned short h1 = f2bf(av1[j]);
            ah0[j] = (short)h0;
            ah1[j] = (short)h1;
            al0[j] = (short)f2bf(av0[j] - bf2f(h0));
            al1[j] = (short)f2bf(av1[j] - bf2f(h1));
        }
#pragma unroll
        for (int f = 0; f < NF; ++f) {
            bf16x8 bh = *(const bf16x8*)&smem[buf][(f * 2 + 0) * 1024 + lane * 16];
            bf16x8 bl = *(const bf16x8*)&smem[buf][(f * 2 + 1) * 1024 + lane * 16];
            acc[0][f] = __builtin_amdgcn_mfma_f32_16x16x32_bf16(al0, bh, acc[0][f], 0, 0, 0);
            acc[0][f] = __builtin_amdgcn_mfma_f32_16x16x32_bf16(ah0, bl, acc[0][f], 0, 0, 0);
            acc[0][f] = __builtin_amdgcn_mfma_f32_16x16x32_bf16(ah0, bh, acc[0][f], 0, 0, 0);
            acc[1][f] = __builtin_amdgcn_mfma_f32_16x16x32_bf16(al1, bh, acc[1][f], 0, 0, 0);
            acc[1][f] = __builtin_amdgcn_mfma_f32_16x16x32_bf16(ah1, bl, acc[1][f], 0, 0, 0);
            acc[1][f] = __builtin_amdgcn_mfma_f32_16x16x32_bf16(ah1, bh, acc[1][f], 0, 0, 0);
        }
        if (kg + 1 < KG) {
#pragma unroll
            for (int j = 0; j < 8; ++j) { av0[j] = nv0[j]; av1[j] = nv1[j]; }
        }
        __syncthreads();
        buf ^= 1;
    }
#undef STAGE1

    // sliced write: [f][row][16]
#pragma unroll
    for (int m = 0; m < 2; m++) {
#pragma unroll
        for (int reg = 0; reg < 4; reg++) {
            int row = r0 + m * 16 + g * 4 + reg;
            if (row < N) {
                float sc = dinv[row];
#pragma unroll
                for (int f = 0; f < NF; f++)
                    Cout[((size_t)f * N + row) * 16 + c] = f2bf(acc[m][f][reg] * sc);
            }
        }
    }
}

// ------- layers 2-4 GEMM: A sliced [8][N][16] bf16; C sliced (SOUT) or row-major ------

template <int K, int M, bool SOUT>
__global__ __launch_bounds__(256) void k_gemm_bf(const unsigned short* __restrict__ A,
                                                 const unsigned short* __restrict__ wpk,
                                                 const float* __restrict__ dinv,
                                                 unsigned short* __restrict__ Cout, int N) {
    constexpr int NF = M / 16;
    constexpr int KG = K / 32;
    constexpr int KGB = NF * 2 * 1024;
    constexpr int NISS = KGB / 4096;
    __shared__ unsigned char smem[2][KGB];

    const int wave = threadIdx.x >> 6;
    const int lane = threadIdx.x & 63;
    const int c = lane & 15, g = lane >> 4;
    const int r0 = blockIdx.x * 128 + wave * 32;

    f32x4 acc[2][NF];
#pragma unroll
    for (int m = 0; m < 2; m++)
#pragma unroll
        for (int f = 0; f < NF; f++) acc[m][f] = (f32x4){0.f, 0.f, 0.f, 0.f};

    const int rA0 = min(r0 + c, N - 1);
    const int rA1 = min(r0 + 16 + c, N - 1);

#define STAGE2(kg_, buf_)                                                              \
    {                                                                                  \
        _Pragma("unroll") for (int i = 0; i < NISS; ++i) {                             \
            const unsigned short* gsrc =                                               \
                wpk + (((size_t)(kg_)*KGB + (size_t)i * 4096 + (size_t)wave * 1024) >> 1) + \
                (size_t)lane * 8;                                                      \
            gload_lds16(gsrc, &smem[buf_][i * 4096 + wave * 1024]);                    \
        }                                                                              \
    }

    STAGE2(0, 0);
    // sliced A fragment: k-col = kg*32 + g*8 -> slice 2*kg + (g>>1), sub-off (g&1)*8
    bf16x8 af0[KG], af1[KG];
#pragma unroll
    for (int kg = 0; kg < KG; ++kg) {
        int sl = 2 * kg + (g >> 1);
        int so = (g & 1) * 8;
        af0[kg] = *(const bf16x8*)(A + ((size_t)sl * N + rA0) * 16 + so);
        af1[kg] = *(const bf16x8*)(A + ((size_t)sl * N + rA1) * 16 + so);
    }
    __syncthreads();

    int buf = 0;
#pragma unroll
    for (int kg = 0; kg < KG; ++kg) {
        if (kg + 1 < KG) STAGE2(kg + 1, buf ^ 1);
#pragma unroll
        for (int f = 0; f < NF; ++f) {
            bf16x8 bh = *(const bf16x8*)&smem[buf][(f * 2 + 0) * 1024 + lane * 16];
            bf16x8 bl = *(const bf16x8*)&smem[buf][(f * 2 + 1) * 1024 + lane * 16];
            acc[0][f] = __builtin_amdgcn_mfma_f32_16x16x32_bf16(af0[kg], bl, acc[0][f], 0, 0, 0);
            acc[0][f] = __builtin_amdgcn_mfma_f32_16x16x32_bf16(af0[kg], bh, acc[0][f], 0, 0, 0);
            acc[1][f] = __builtin_amdgcn_mfma_f32_16x16x32_bf16(af1[kg], bl, acc[1][f], 0, 0, 0);
            acc[1][f] = __builtin_amdgcn_mfma_f32_16x16x32_bf16(af1[kg], bh, acc[1][f], 0, 0, 0);
        }
        __syncthreads();
        buf ^= 1;
    }
#undef STAGE2

#pragma unroll
    for (int m = 0; m < 2; m++) {
#pragma unroll
        for (int reg = 0; reg < 4; reg++) {
            int row = r0 + m * 16 + g * 4 + reg;
            if (row < N) {
                float sc = dinv[row];
#pragma unroll
                for (int f = 0; f < NF; f++) {
                    unsigned short v = f2bf(acc[m][f][reg] * sc);
                    if (SOUT) Cout[((size_t)f * N + row) * 16 + c] = v;
                    else      Cout[(size_t)row * M + f * 16 + c] = v;
                }
            }
        }
    }
}

// ---- sliced aggregate: out[s][n][:] = relu(dn*(g[s][n]+Σ g[s][src]) + b_s) ----
// slice = blockIdx.x & 7 -> pins each 3.2MB slice to one XCD's L2 (round-robin dispatch).
// 8 lanes per node (one uint = 2 bf16 features each), 32 nodes per block.

__global__ __launch_bounds__(256) void k_aggslc(const unsigned* __restrict__ g,
                                                const int* __restrict__ offs,
                                                const int* __restrict__ ssrc,
                                                const float* __restrict__ dinv,
                                                const float* __restrict__ bias,
                                                unsigned* __restrict__ out, int N) {
    const int slice = blockIdx.x & 7;
    const int nb = blockIdx.x >> 3;
    const int t = threadIdx.x;
    const int grp = t >> 3;        // node within block (0..31)
    const int q = t & 7;           // uint within 16-feature slice row
    const int n = nb * 32 + grp;
    if (n >= N) return;

    const unsigned* gs = g + (size_t)slice * N * 8;
    const float dn = dinv[n];
    unsigned u = gs[(size_t)n * 8 + q];       // self (already dinv-scaled)
    float ax = bflo(u), ay = bfhi(u);
    const int e0 = offs[n], e1 = offs[n + 1];
    int j = e0;
    for (; j + 4 <= e1; j += 4) {
        int s0 = ssrc[j], s1 = ssrc[j + 1], s2 = ssrc[j + 2], s3 = ssrc[j + 3];
        unsigned u0 = gs[(size_t)s0 * 8 + q];
        unsigned u1 = gs[(size_t)s1 * 8 + q];
        unsigned u2 = gs[(size_t)s2 * 8 + q];
        unsigned u3 = gs[(size_t)s3 * 8 + q];
        ax += bflo(u0); ay += bfhi(u0);
        ax += bflo(u1); ay += bfhi(u1);
        ax += bflo(u2); ay += bfhi(u2);
        ax += bflo(u3); ay += bfhi(u3);
    }
    for (; j < e1; ++j) {
        unsigned uu = gs[(size_t)ssrc[j] * 8 + q];
        ax += bflo(uu); ay += bfhi(uu);
    }
    float2 b = ((const float2*)bias)[slice * 8 + q];
    float ox = fmaxf(fmaf(dn, ax, b.x), 0.f);
    float oy = fmaxf(fmaf(dn, ay, b.y), 0.f);
    out[(size_t)slice * N * 8 + (size_t)n * 8 + q] =
        ((unsigned)f2bf(oy) << 16) | (unsigned)f2bf(ox);
}

// ---------------- final aggregate (M=64, bf16 rows) + log_softmax, fp32 out ----------------

__global__ __launch_bounds__(256) void k_agg64f(const unsigned short* __restrict__ g,
                                                const int* __restrict__ offs,
                                                const int* __restrict__ ssrc,
                                                const float* __restrict__ dinv,
                                                const float* __restrict__ bias,
                                                float* __restrict__ out, int N) {
    int wid = (int)(((size_t)blockIdx.x * blockDim.x + threadIdx.x) >> 6);
    int lane = threadIdx.x & 63;
    if (wid >= N) return;
    const int n = wid;
    const float dn = dinv[n];
    float acc = bf2f(g[(size_t)n * 64 + lane]);
    const int e0 = offs[n], e1 = offs[n + 1];
    int j = e0;
    for (; j + 8 <= e1; j += 8) {
        int sv[8];
#pragma unroll
        for (int q = 0; q < 8; q++) sv[q] = ssrc[j + q];
        float fv[8];
#pragma unroll
        for (int q = 0; q < 8; q++) fv[q] = bf2f(g[(size_t)sv[q] * 64 + lane]);
#pragma unroll
        for (int q = 0; q < 8; q++) acc += fv[q];
    }
    for (; j < e1; ++j) acc += bf2f(g[(size_t)ssrc[j] * 64 + lane]);
    float v = fmaxf(fmaf(dn, acc, bias[lane]), 0.f);
    float m = v;
#pragma unroll
    for (int d = 1; d < 64; d <<= 1) m = fmaxf(m, __shfl_xor(m, d));
    float ex = expf(v - m);
    float ssum = ex;
#pragma unroll
    for (int d = 1; d < 64; d <<= 1) ssum += __shfl_xor(ssum, d);
    out[(size_t)n * 64 + lane] = v - m - logf(ssum);
}

// ---------------- launcher ----------------

extern "C" void kernel_launch(void* const* d_in, const int* in_sizes, int n_in,
                              void* d_out, int out_size, void* d_ws, size_t ws_size,
                              hipStream_t stream) {
    const float* x  = (const float*)d_in[0];
    const int*   ei = (const int*)d_in[1];
    const float* W1 = (const float*)d_in[2];
    const float* b1 = (const float*)d_in[3];
    const float* W2 = (const float*)d_in[4];
    const float* b2 = (const float*)d_in[5];
    const float* W3 = (const float*)d_in[6];
    const float* b3 = (const float*)d_in[7];
    const float* W4 = (const float*)d_in[8];
    const float* b4 = (const float*)d_in[9];

    const int N = in_sizes[0] / IN_DIM;     // 100000
    const int E = in_sizes[1] / 2;          // 1600000
    const int nbuk = (N + (1 << BUKSH) - 1) >> BUKSH;   // 98
    const int* src = ei;
    const int* dst = ei + E;

    char* p = (char*)d_ws;
    unsigned short* hbf = (unsigned short*)p; p += (size_t)N * HID * 2;     // gemm out (sliced bf16)
    unsigned short* abf = (unsigned short*)p; p += (size_t)N * HID * 2;     // agg out (sliced bf16)
    unsigned short* h4  = (unsigned short*)p; p += (size_t)N * OUT_DIM * 2; // gemm4 out (row-major)
    float* dinv = (float*)p;          p += (size_t)N * sizeof(float);
    int* counts = (int*)p;            p += (size_t)N * sizeof(int);
    int* bcur   = (int*)p;            p += (size_t)nbuk * sizeof(int);
    int* offs   = (int*)p;            p += (size_t)(N + 1) * sizeof(int);
    int* bsums  = (int*)p;            p += 256 * sizeof(int);
    int* ssrc   = (int*)p;            p += (size_t)E * sizeof(int);
    unsigned* ebuf = (unsigned*)p;    p += (size_t)nbuk * BCAP2 * sizeof(unsigned);
    unsigned short* w1p = (unsigned short*)p; p += (size_t)IN_DIM * HID * 2 * 2;
    unsigned short* w2p = (unsigned short*)p; p += (size_t)HID * HID * 2 * 2;
    unsigned short* w3p = (unsigned short*)p; p += (size_t)HID * HID * 2 * 2;
    unsigned short* w4p = (unsigned short*)p; p += (size_t)HID * OUT_DIM * 2 * 2;

    hipMemsetAsync(bcur, 0, (size_t)nbuk * sizeof(int), stream);

    const int nb = (N + 1023) / 1024;
    const int nchunks = (E + EPB - 1) / EPB;
    k_bucket2<<<nchunks, 256, 0, stream>>>(src, dst, E, nbuk, bcur, ebuf);
    k_hist2<<<nbuk, 256, 0, stream>>>(ebuf, bcur, N, counts);
    k_scan1<<<nb, 1024, 0, stream>>>(counts, N, offs, bsums);
    k_scan2<<<1, 256, 0, stream>>>(bsums, nb);
    k_scan3<<<nb, 1024, 0, stream>>>(offs, bsums, N, E);
    k_dinv<<<(N + 255) / 256, 256, 0, stream>>>(counts, N, dinv);
    k_csr2<<<nbuk, 256, 0, stream>>>(ebuf, bcur, offs, N, ssrc);

    k_packW<<<(IN_DIM * HID * 2 + 255) / 256, 256, 0, stream>>>(W1, IN_DIM, HID, w1p);
    k_packW<<<(HID * HID * 2 + 255) / 256, 256, 0, stream>>>(W2, HID, HID, w2p);
    k_packW<<<(HID * HID * 2 + 255) / 256, 256, 0, stream>>>(W3, HID, HID, w3p);
    k_packW<<<(HID * OUT_DIM * 2 + 255) / 256, 256, 0, stream>>>(W4, HID, OUT_DIM, w4p);

    const int gb = (N + 127) / 128;           // gemm: 128 rows / block
    const int ab = (N + 3) / 4;               // agg64f: 4 nodes / block
    const int sb = ((N + 31) / 32) * 8;       // sliced agg: 32 nodes x 8 slices
    k_gemm1<IN_DIM, HID><<<gb, 256, 0, stream>>>(x, w1p, dinv, hbf, N);
    k_aggslc<<<sb, 256, 0, stream>>>((const unsigned*)hbf, offs, ssrc, dinv, b1, (unsigned*)abf, N);
    k_gemm_bf<HID, HID, true><<<gb, 256, 0, stream>>>(abf, w2p, dinv, hbf, N);
    k_aggslc<<<sb, 256, 0, stream>>>((const unsigned*)hbf, offs, ssrc, dinv, b2, (unsigned*)abf, N);
    k_gemm_bf<HID, HID, true><<<gb, 256, 0, stream>>>(abf, w3p, dinv, hbf, N);
    k_aggslc<<<sb, 256, 0, stream>>>((const unsigned*)hbf, offs, ssrc, dinv, b3, (unsigned*)abf, N);
    k_gemm_bf<HID, OUT_DIM, false><<<gb, 256, 0, stream>>>(abf, w4p, dinv, h4, N);
    k_agg64f<<<ab, 256, 0, stream>>>(h4, offs, ssrc, dinv, b4, (float*)d_out, N);
}

// Round 10
// 500.099 us; speedup vs baseline: 1.0664x; 1.0664x over previous
//
#include <hip/hip_runtime.h>
#include <cstdint>
#include <cstddef>

static constexpr int IN_DIM = 512;
static constexpr int HID = 128;
static constexpr int OUT_DIM = 64;

// CSR build params
static constexpr int BUKSH = 10;          // 1024 nodes per coarse bucket
static constexpr int MAXBUK = 128;        // >= nbuk = ceil(N/1024) = 98
static constexpr int BINCAP = 96;         // LDS bin capacity (avg fill ~42)
static constexpr int EPB = 4096;          // edges per block in phase 1
static constexpr int BCAP2 = 24576;       // ebuf capacity per bucket (avg 16.3k)

typedef __attribute__((ext_vector_type(8))) short bf16x8;
typedef __attribute__((ext_vector_type(4))) float f32x4;

__device__ inline unsigned short f2bf(float x) {
    unsigned u = __float_as_uint(x);
    unsigned r = (u + 0x7FFFu + ((u >> 16) & 1u)) >> 16;   // RNE
    return (unsigned short)r;
}
__device__ inline float bf2f(unsigned short b) { return __uint_as_float(((unsigned)b) << 16); }
__device__ inline float bflo(unsigned u) { return __uint_as_float(u << 16); }
__device__ inline float bfhi(unsigned u) { return __uint_as_float(u & 0xFFFF0000u); }

__device__ inline void gload_lds16(const void* g, void* l) {
    __builtin_amdgcn_global_load_lds(
        (const __attribute__((address_space(1))) unsigned int*)g,
        (__attribute__((address_space(3))) unsigned int*)(unsigned long long)(uintptr_t)l,
        16, 0, 0);
}

// ============ CSR construction: LDS-binned bucket sort (rebuilt every call) ============
// entry pack: src (bits 0-16) | (dst & 1023) << 17

__global__ __launch_bounds__(256) void k_bucket2(const int* __restrict__ src,
                                                 const int* __restrict__ dst, int E, int nbuk,
                                                 int* __restrict__ bcur,
                                                 unsigned* __restrict__ ebuf) {
    __shared__ int bincnt[MAXBUK];
    __shared__ int binbase[MAXBUK];
    __shared__ unsigned binbuf[MAXBUK][BINCAP];
    const int t = threadIdx.x;
    for (int i = t; i < MAXBUK; i += 256) bincnt[i] = 0;
    __syncthreads();

    const int e0 = blockIdx.x * EPB;
#pragma unroll
    for (int q = 0; q < EPB / 256; q++) {
        int e = e0 + q * 256 + t;
        if (e < E) {
            int s = src[e], d = dst[e];
            int b = d >> BUKSH;
            unsigned v = (unsigned)s | ((unsigned)(d & ((1 << BUKSH) - 1)) << 17);
            int pos = atomicAdd(&bincnt[b], 1);
            if (pos < BINCAP) {
                binbuf[b][pos] = v;
            } else {
                int p = atomicAdd(&bcur[b], 1);
                if (p < BCAP2) ebuf[(size_t)b * BCAP2 + p] = v;
            }
        }
    }
    __syncthreads();

    if (t < MAXBUK) {
        int c = (t < nbuk) ? min(bincnt[t], BINCAP) : 0;
        binbase[t] = c ? atomicAdd(&bcur[t], c) : 0;
        bincnt[t] = c;
    }
    __syncthreads();

    const int wave = t >> 6, lane = t & 63;
    for (int b = wave; b < nbuk; b += 4) {
        int c = bincnt[b];
        int base = binbase[b];
        int cc = min(c, max(0, BCAP2 - base));
        for (int i = lane; i < cc; i += 64)
            ebuf[(size_t)b * BCAP2 + base + i] = binbuf[b][i];
    }
}

__global__ __launch_bounds__(256) void k_hist2(const unsigned* __restrict__ ebuf,
                                               const int* __restrict__ bcur, int N,
                                               int* __restrict__ counts) {
    __shared__ int lcnt[1 << BUKSH];
    const int b = blockIdx.x, t = threadIdx.x;
    for (int i = t; i < (1 << BUKSH); i += 256) lcnt[i] = 0;
    __syncthreads();
    const int cnt = min(bcur[b], BCAP2);
    const unsigned* eb = ebuf + (size_t)b * BCAP2;
    for (int i = t; i < cnt; i += 256) atomicAdd(&lcnt[eb[i] >> 17], 1);
    __syncthreads();
    const int n0 = b << BUKSH;
    for (int i = t; i < (1 << BUKSH); i += 256)
        if (n0 + i < N) counts[n0 + i] = lcnt[i];
}

__global__ void k_scan1(const int* __restrict__ counts, int N, int* __restrict__ offs,
                        int* __restrict__ bsums) {
    __shared__ int sm[1024];
    int i = blockIdx.x * 1024 + threadIdx.x;
    int v = (i < N) ? counts[i] : 0;
    sm[threadIdx.x] = v;
    __syncthreads();
    for (int d = 1; d < 1024; d <<= 1) {
        int t = (threadIdx.x >= d) ? sm[threadIdx.x - d] : 0;
        __syncthreads();
        sm[threadIdx.x] += t;
        __syncthreads();
    }
    if (i < N) offs[i] = sm[threadIdx.x] - v;
    if (threadIdx.x == 1023) bsums[blockIdx.x] = sm[1023];
}

__global__ void k_scan2(int* __restrict__ bsums, int nb) {
    __shared__ int sm[256];
    int x = threadIdx.x;
    int v = (x < nb) ? bsums[x] : 0;
    sm[x] = v;
    __syncthreads();
    for (int d = 1; d < 256; d <<= 1) {
        int t = (x >= d) ? sm[x - d] : 0;
        __syncthreads();
        sm[x] += t;
        __syncthreads();
    }
    if (x < nb) bsums[x] = sm[x] - v;
}

__global__ void k_scan3(int* __restrict__ offs, const int* __restrict__ bsums, int N, int E) {
    int i = blockIdx.x * 1024 + threadIdx.x;
    if (i < N) offs[i] += bsums[blockIdx.x];
    if (blockIdx.x == 0 && threadIdx.x == 0) offs[N] = E;
}

__global__ void k_dinv(const int* __restrict__ counts, int N, float* __restrict__ dinv) {
    int i = blockIdx.x * blockDim.x + threadIdx.x;
    if (i < N) dinv[i] = rsqrtf((float)(counts[i] + 1));
}

__global__ __launch_bounds__(256) void k_csr2(const unsigned* __restrict__ ebuf,
                                              const int* __restrict__ bcur,
                                              const int* __restrict__ offs, int N,
                                              int* __restrict__ ssrc) {
    __shared__ int lcur[1 << BUKSH];
    const int b = blockIdx.x, t = threadIdx.x;
    const int n0 = b << BUKSH;
    for (int i = t; i < (1 << BUKSH); i += 256)
        lcur[i] = (n0 + i < N) ? offs[n0 + i] : 0;
    __syncthreads();
    const int cnt = min(bcur[b], BCAP2);
    const unsigned* eb = ebuf + (size_t)b * BCAP2;
    for (int i = t; i < cnt; i += 256) {
        unsigned v = eb[i];
        int p = atomicAdd(&lcur[v >> 17], 1);
        ssrc[p] = (int)(v & 0x1FFFFu);
    }
}

// ---- sort each node's edge list by src (one wave per node, 64-wide bitonic) ----
// Quasi-sequential gathers: resident waves at edge-step j access the j-th order
// statistic of uniform srcs -> moving window over the h table instead of uniform random.

__global__ __launch_bounds__(256) void k_sortcsr(const int* __restrict__ offs, int N,
                                                 int* __restrict__ ssrc) {
    int wid = (int)(((size_t)blockIdx.x * blockDim.x + threadIdx.x) >> 6);
    int lane = threadIdx.x & 63;
    if (wid >= N) return;
    const int e0 = offs[wid], e1 = offs[wid + 1];
    const int deg = e1 - e0;
    if (deg < 3 || deg > 64) return;          // rare tails left unsorted (correct either way)
    int v = (lane < deg) ? ssrc[e0 + lane] : 0x7FFFFFFF;
#pragma unroll
    for (int k = 2; k <= 64; k <<= 1) {
#pragma unroll
        for (int j = k >> 1; j > 0; j >>= 1) {
            int o = __shfl_xor(v, j);
            bool up = ((lane & k) == 0);
            bool lower = ((lane & j) == 0);
            v = ((up == lower) ? min(v, o) : max(v, o));
        }
    }
    if (lane < deg) ssrc[e0 + lane] = v;
}

// ---------------- W pack: per-kg contiguous MFMA B-fragment blocks (hi/lo interleaved) -------

__global__ void k_packW(const float* __restrict__ W, int K, int M,
                        unsigned short* __restrict__ wpk) {
    int idx = blockIdx.x * 256 + threadIdx.x;
    int total = K * M * 2;
    if (idx >= total) return;
    int j = idx & 7;
    int l = (idx >> 3) & 63;
    int h = (idx >> 9) & 1;
    int rest = idx >> 10;
    int NF = M >> 4;
    int f = rest % NF;
    int kg = rest / NF;
    int k = kg * 32 + (l >> 4) * 8 + j;
    int col = f * 16 + (l & 15);
    float v = W[(size_t)k * M + col];
    unsigned short hi = f2bf(v);
    wpk[idx] = h ? f2bf(v - bf2f(hi)) : hi;
}

// ------- layer-1 GEMM: C_bf16 = dinv ⊙ (A_f32[N,K] @ W[K,M]); 3-term split, LDS-staged B -----

template <int K, int M>
__global__ __launch_bounds__(256) void k_gemm1(const float* __restrict__ A,
                                               const unsigned short* __restrict__ wpk,
                                               const float* __restrict__ dinv,
                                               unsigned short* __restrict__ Cout, int N) {
    constexpr int NF = M / 16;
    constexpr int KG = K / 32;
    constexpr int KGB = NF * 2 * 1024;
    constexpr int NISS = KGB / 4096;
    __shared__ unsigned char smem[2][KGB];

    const int wave = threadIdx.x >> 6;
    const int lane = threadIdx.x & 63;
    const int c = lane & 15, g = lane >> 4;
    const int r0 = blockIdx.x * 128 + wave * 32;

    f32x4 acc[2][NF];
#pragma unroll
    for (int m = 0; m < 2; m++)
#pragma unroll
        for (int f = 0; f < NF; f++) acc[m][f] = (f32x4){0.f, 0.f, 0.f, 0.f};

    const int rA0 = min(r0 + c, N - 1);
    const int rA1 = min(r0 + 16 + c, N - 1);
    const float* ap0 = A + (size_t)rA0 * K + g * 8;
    const float* ap1 = A + (size_t)rA1 * K + g * 8;

#define STAGE1(kg_, buf_)                                                              \
    {                                                                                  \
        _Pragma("unroll") for (int i = 0; i < NISS; ++i) {                             \
            const unsigned short* gsrc =                                               \
                wpk + (((size_t)(kg_)*KGB + (size_t)i * 4096 + (size_t)wave * 1024) >> 1) + \
                (size_t)lane * 8;                                                      \
            gload_lds16(gsrc, &smem[buf_][i * 4096 + wave * 1024]);                    \
        }                                                                              \
    }

    STAGE1(0, 0);
    float av0[8], av1[8];
    *(float4*)&av0[0] = *(const float4*)(ap0);
    *(float4*)&av0[4] = *(const float4*)(ap0 + 4);
    *(float4*)&av1[0] = *(const float4*)(ap1);
    *(float4*)&av1[4] = *(const float4*)(ap1 + 4);
    __syncthreads();

    int buf = 0;
    for (int kg = 0; kg < KG; ++kg) {
        if (kg + 1 < KG) STAGE1(kg + 1, buf ^ 1);
        float nv0[8], nv1[8];
        if (kg + 1 < KG) {
            *(float4*)&nv0[0] = *(const float4*)(ap0 + (kg + 1) * 32);
            *(float4*)&nv0[4] = *(const float4*)(ap0 + (kg + 1) * 32 + 4);
            *(float4*)&nv1[0] = *(const float4*)(ap1 + (kg + 1) * 32);
            *(float4*)&nv1[4] = *(const float4*)(ap1 + (kg + 1) * 32 + 4);
        }
        bf16x8 ah0, al0, ah1, al1;
#pragma unroll
        for (int j = 0; j < 8; ++j) {
            unsigned short h0 = f2bf(av0[j]);
            unsigned short h1 = f2bf(av1[j]);
            ah0[j] = (short)h0;
            ah1[j] = (short)h1;
            al0[j] = (short)f2bf(av0[j] - bf2f(h0));
            al1[j] = (short)f2bf(av1[j] - bf2f(h1));
        }
#pragma unroll
        for (int f = 0; f < NF; ++f) {
            bf16x8 bh = *(const bf16x8*)&smem[buf][(f * 2 + 0) * 1024 + lane * 16];
            bf16x8 bl = *(const bf16x8*)&smem[buf][(f * 2 + 1) * 1024 + lane * 16];
            acc[0][f] = __builtin_amdgcn_mfma_f32_16x16x32_bf16(al0, bh, acc[0][f], 0, 0, 0);
            acc[0][f] = __builtin_amdgcn_mfma_f32_16x16x32_bf16(ah0, bl, acc[0][f], 0, 0, 0);
            acc[0][f] = __builtin_amdgcn_mfma_f32_16x16x32_bf16(ah0, bh, acc[0][f], 0, 0, 0);
            acc[1][f] = __builtin_amdgcn_mfma_f32_16x16x32_bf16(al1, bh, acc[1][f], 0, 0, 0);
            acc[1][f] = __builtin_amdgcn_mfma_f32_16x16x32_bf16(ah1, bl, acc[1][f], 0, 0, 0);
            acc[1][f] = __builtin_amdgcn_mfma_f32_16x16x32_bf16(ah1, bh, acc[1][f], 0, 0, 0);
        }
        if (kg + 1 < KG) {
#pragma unroll
            for (int j = 0; j < 8; ++j) { av0[j] = nv0[j]; av1[j] = nv1[j]; }
        }
        __syncthreads();
        buf ^= 1;
    }
#undef STAGE1

#pragma unroll
    for (int m = 0; m < 2; m++) {
#pragma unroll
        for (int reg = 0; reg < 4; reg++) {
            int row = r0 + m * 16 + g * 4 + reg;
            if (row < N) {
                float sc = dinv[row];
#pragma unroll
                for (int f = 0; f < NF; f++)
                    Cout[(size_t)row * M + f * 16 + c] = f2bf(acc[m][f][reg] * sc);
            }
        }
    }
}

// ------- layers 2-4 GEMM: C_bf16 = dinv ⊙ (A_bf16[N,K] @ W[K,M]); 2-term, LDS-staged B ------

template <int K, int M>
__global__ __launch_bounds__(256) void k_gemm_bf(const unsigned short* __restrict__ A,
                                                 const unsigned short* __restrict__ wpk,
                                                 const float* __restrict__ dinv,
                                                 unsigned short* __restrict__ Cout, int N) {
    constexpr int NF = M / 16;
    constexpr int KG = K / 32;
    constexpr int KGB = NF * 2 * 1024;
    constexpr int NISS = KGB / 4096;
    __shared__ unsigned char smem[2][KGB];

    const int wave = threadIdx.x >> 6;
    const int lane = threadIdx.x & 63;
    const int c = lane & 15, g = lane >> 4;
    const int r0 = blockIdx.x * 128 + wave * 32;

    f32x4 acc[2][NF];
#pragma unroll
    for (int m = 0; m < 2; m++)
#pragma unroll
        for (int f = 0; f < NF; f++) acc[m][f] = (f32x4){0.f, 0.f, 0.f, 0.f};

    const int rA0 = min(r0 + c, N - 1);
    const int rA1 = min(r0 + 16 + c, N - 1);
    const unsigned short* ap0 = A + (size_t)rA0 * K + g * 8;
    const unsigned short* ap1 = A + (size_t)rA1 * K + g * 8;

#define STAGE2(kg_, buf_)                                                              \
    {                                                                                  \
        _Pragma("unroll") for (int i = 0; i < NISS; ++i) {                             \
            const unsigned short* gsrc =                                               \
                wpk + (((size_t)(kg_)*KGB + (size_t)i * 4096 + (size_t)wave * 1024) >> 1) + \
                (size_t)lane * 8;                                                      \
            gload_lds16(gsrc, &smem[buf_][i * 4096 + wave * 1024]);                    \
        }                                                                              \
    }

    STAGE2(0, 0);
    bf16x8 af0[KG], af1[KG];
#pragma unroll
    for (int kg = 0; kg < KG; ++kg) {
        af0[kg] = *(const bf16x8*)(ap0 + kg * 32);
        af1[kg] = *(const bf16x8*)(ap1 + kg * 32);
    }
    __syncthreads();

    int buf = 0;
#pragma unroll
    for (int kg = 0; kg < KG; ++kg) {
        if (kg + 1 < KG) STAGE2(kg + 1, buf ^ 1);
#pragma unroll
        for (int f = 0; f < NF; ++f) {
            bf16x8 bh = *(const bf16x8*)&smem[buf][(f * 2 + 0) * 1024 + lane * 16];
            bf16x8 bl = *(const bf16x8*)&smem[buf][(f * 2 + 1) * 1024 + lane * 16];
            acc[0][f] = __builtin_amdgcn_mfma_f32_16x16x32_bf16(af0[kg], bl, acc[0][f], 0, 0, 0);
            acc[0][f] = __builtin_amdgcn_mfma_f32_16x16x32_bf16(af0[kg], bh, acc[0][f], 0, 0, 0);
            acc[1][f] = __builtin_amdgcn_mfma_f32_16x16x32_bf16(af1[kg], bl, acc[1][f], 0, 0, 0);
            acc[1][f] = __builtin_amdgcn_mfma_f32_16x16x32_bf16(af1[kg], bh, acc[1][f], 0, 0, 0);
        }
        __syncthreads();
        buf ^= 1;
    }
#undef STAGE2

#pragma unroll
    for (int m = 0; m < 2; m++) {
#pragma unroll
        for (int reg = 0; reg < 4; reg++) {
            int row = r0 + m * 16 + g * 4 + reg;
            if (row < N) {
                float sc = dinv[row];
#pragma unroll
                for (int f = 0; f < NF; f++)
                    Cout[(size_t)row * M + f * 16 + c] = f2bf(acc[m][f][reg] * sc);
            }
        }
    }
}

// ---- aggregate (M=128, bf16 rows in AND out): out = relu(dn*(g[n]+Σ g[src]) + b) ----

__global__ __launch_bounds__(256) void k_aggbf(const unsigned* __restrict__ g,
                                               const int* __restrict__ offs,
                                               const int* __restrict__ ssrc,
                                               const float* __restrict__ dinv,
                                               const float* __restrict__ bias,
                                               unsigned* __restrict__ out, int N) {
    int wid = (int)(((size_t)blockIdx.x * blockDim.x + threadIdx.x) >> 6);
    int lane = threadIdx.x & 63;
    if (wid >= N) return;
    const int n = wid;
    const float dn = dinv[n];
    unsigned u = g[(size_t)n * 64 + lane];
    float ax = bflo(u), ay = bfhi(u);
    const int e0 = offs[n], e1 = offs[n + 1];
    int j = e0;
    for (; j + 8 <= e1; j += 8) {
        int sv[8];
#pragma unroll
        for (int q = 0; q < 8; q++) sv[q] = ssrc[j + q];
        unsigned uv[8];
#pragma unroll
        for (int q = 0; q < 8; q++) uv[q] = g[(size_t)sv[q] * 64 + lane];
#pragma unroll
        for (int q = 0; q < 8; q++) { ax += bflo(uv[q]); ay += bfhi(uv[q]); }
    }
    if (j + 4 <= e1) {
        int sv[4];
#pragma unroll
        for (int q = 0; q < 4; q++) sv[q] = ssrc[j + q];
        unsigned uv[4];
#pragma unroll
        for (int q = 0; q < 4; q++) uv[q] = g[(size_t)sv[q] * 64 + lane];
#pragma unroll
        for (int q = 0; q < 4; q++) { ax += bflo(uv[q]); ay += bfhi(uv[q]); }
        j += 4;
    }
    for (; j < e1; ++j) {
        unsigned uu = g[(size_t)ssrc[j] * 64 + lane];
        ax += bflo(uu); ay += bfhi(uu);
    }
    float2 b = ((const float2*)bias)[lane];
    float ox = fmaxf(fmaf(dn, ax, b.x), 0.f);
    float oy = fmaxf(fmaf(dn, ay, b.y), 0.f);
    out[(size_t)n * 64 + lane] = ((unsigned)f2bf(oy) << 16) | (unsigned)f2bf(ox);
}

// ---------------- final aggregate (M=64, bf16 rows) + log_softmax, fp32 out ----------------

__global__ __launch_bounds__(256) void k_agg64f(const unsigned short* __restrict__ g,
                                                const int* __restrict__ offs,
                                                const int* __restrict__ ssrc,
                                                const float* __restrict__ dinv,
                                                const float* __restrict__ bias,
                                                float* __restrict__ out, int N) {
    int wid = (int)(((size_t)blockIdx.x * blockDim.x + threadIdx.x) >> 6);
    int lane = threadIdx.x & 63;
    if (wid >= N) return;
    const int n = wid;
    const float dn = dinv[n];
    float acc = bf2f(g[(size_t)n * 64 + lane]);
    const int e0 = offs[n], e1 = offs[n + 1];
    int j = e0;
    for (; j + 8 <= e1; j += 8) {
        int sv[8];
#pragma unroll
        for (int q = 0; q < 8; q++) sv[q] = ssrc[j + q];
        float fv[8];
#pragma unroll
        for (int q = 0; q < 8; q++) fv[q] = bf2f(g[(size_t)sv[q] * 64 + lane]);
#pragma unroll
        for (int q = 0; q < 8; q++) acc += fv[q];
    }
    for (; j < e1; ++j) acc += bf2f(g[(size_t)ssrc[j] * 64 + lane]);
    float v = fmaxf(fmaf(dn, acc, bias[lane]), 0.f);
    float m = v;
#pragma unroll
    for (int d = 1; d < 64; d <<= 1) m = fmaxf(m, __shfl_xor(m, d));
    float ex = expf(v - m);
    float ssum = ex;
#pragma unroll
    for (int d = 1; d < 64; d <<= 1) ssum += __shfl_xor(ssum, d);
    out[(size_t)n * 64 + lane] = v - m - logf(ssum);
}

// ---------------- launcher ----------------

extern "C" void kernel_launch(void* const* d_in, const int* in_sizes, int n_in,
                              void* d_out, int out_size, void* d_ws, size_t ws_size,
                              hipStream_t stream) {
    const float* x  = (const float*)d_in[0];
    const int*   ei = (const int*)d_in[1];
    const float* W1 = (const float*)d_in[2];
    const float* b1 = (const float*)d_in[3];
    const float* W2 = (const float*)d_in[4];
    const float* b2 = (const float*)d_in[5];
    const float* W3 = (const float*)d_in[6];
    const float* b3 = (const float*)d_in[7];
    const float* W4 = (const float*)d_in[8];
    const float* b4 = (const float*)d_in[9];

    const int N = in_sizes[0] / IN_DIM;     // 100000
    const int E = in_sizes[1] / 2;          // 1600000
    const int nbuk = (N + (1 << BUKSH) - 1) >> BUKSH;   // 98
    const int* src = ei;
    const int* dst = ei + E;

    char* p = (char*)d_ws;
    unsigned short* hbf = (unsigned short*)p; p += (size_t)N * HID * 2;     // gemm out (bf16)
    unsigned short* abf = (unsigned short*)p; p += (size_t)N * HID * 2;     // agg out (bf16)
    unsigned short* h4  = (unsigned short*)p; p += (size_t)N * OUT_DIM * 2; // gemm4 out (bf16)
    float* dinv = (float*)p;          p += (size_t)N * sizeof(float);
    int* counts = (int*)p;            p += (size_t)N * sizeof(int);
    int* bcur   = (int*)p;            p += (size_t)nbuk * sizeof(int);
    int* offs   = (int*)p;            p += (size_t)(N + 1) * sizeof(int);
    int* bsums  = (int*)p;            p += 256 * sizeof(int);
    int* ssrc   = (int*)p;            p += (size_t)E * sizeof(int);
    unsigned* ebuf = (unsigned*)p;    p += (size_t)nbuk * BCAP2 * sizeof(unsigned);
    unsigned short* w1p = (unsigned short*)p; p += (size_t)IN_DIM * HID * 2 * 2;
    unsigned short* w2p = (unsigned short*)p; p += (size_t)HID * HID * 2 * 2;
    unsigned short* w3p = (unsigned short*)p; p += (size_t)HID * HID * 2 * 2;
    unsigned short* w4p = (unsigned short*)p; p += (size_t)HID * OUT_DIM * 2 * 2;

    (void)hipMemsetAsync(bcur, 0, (size_t)nbuk * sizeof(int), stream);

    const int nb = (N + 1023) / 1024;
    const int nchunks = (E + EPB - 1) / EPB;
    k_bucket2<<<nchunks, 256, 0, stream>>>(src, dst, E, nbuk, bcur, ebuf);
    k_hist2<<<nbuk, 256, 0, stream>>>(ebuf, bcur, N, counts);
    k_scan1<<<nb, 1024, 0, stream>>>(counts, N, offs, bsums);
    k_scan2<<<1, 256, 0, stream>>>(bsums, nb);
    k_scan3<<<nb, 1024, 0, stream>>>(offs, bsums, N, E);
    k_dinv<<<(N + 255) / 256, 256, 0, stream>>>(counts, N, dinv);
    k_csr2<<<nbuk, 256, 0, stream>>>(ebuf, bcur, offs, N, ssrc);
    k_sortcsr<<<(N + 3) / 4, 256, 0, stream>>>(offs, N, ssrc);

    k_packW<<<(IN_DIM * HID * 2 + 255) / 256, 256, 0, stream>>>(W1, IN_DIM, HID, w1p);
    k_packW<<<(HID * HID * 2 + 255) / 256, 256, 0, stream>>>(W2, HID, HID, w2p);
    k_packW<<<(HID * HID * 2 + 255) / 256, 256, 0, stream>>>(W3, HID, HID, w3p);
    k_packW<<<(HID * OUT_DIM * 2 + 255) / 256, 256, 0, stream>>>(W4, HID, OUT_DIM, w4p);

    const int gb = (N + 127) / 128;    // 128 rows / block (32 per wave)
    const int ab = (N + 3) / 4;
    k_gemm1<IN_DIM, HID><<<gb, 256, 0, stream>>>(x, w1p, dinv, hbf, N);
    k_aggbf<<<ab, 256, 0, stream>>>((const unsigned*)hbf, offs, ssrc, dinv, b1, (unsigned*)abf, N);
    k_gemm_bf<HID, HID><<<gb, 256, 0, stream>>>(abf, w2p, dinv, hbf, N);
    k_aggbf<<<ab, 256, 0, stream>>>((const unsigned*)hbf, offs, ssrc, dinv, b2, (unsigned*)abf, N);
    k_gemm_bf<HID, HID><<<gb, 256, 0, stream>>>(abf, w3p, dinv, hbf, N);
    k_aggbf<<<ab, 256, 0, stream>>>((const unsigned*)hbf, offs, ssrc, dinv, b3, (unsigned*)abf, N);
    k_gemm_bf<HID, OUT_DIM><<<gb, 256, 0, stream>>>(abf, w4p, dinv, h4, N);
    k_agg64f<<<ab, 256, 0, stream>>>(h4, offs, ssrc, dinv, b4, (float*)d_out, N);
}

// Round 11
// 470.246 us; speedup vs baseline: 1.1341x; 1.0635x over previous
//
#include <hip/hip_runtime.h>
#include <cstdint>
#include <cstddef>

static constexpr int IN_DIM = 512;
static constexpr int HID = 128;
static constexpr int OUT_DIM = 64;

// CSR build params
static constexpr int BUKSH = 10;          // 1024 nodes per coarse bucket
static constexpr int MAXBUK = 128;        // >= nbuk = ceil(N/1024) = 98
static constexpr int BINCAP = 96;         // LDS bin capacity (avg fill ~42)
static constexpr int EPB = 4096;          // edges per block in phase 1
static constexpr int BCAP2 = 24576;       // ebuf capacity per bucket (avg 16.3k)

typedef __attribute__((ext_vector_type(8))) short bf16x8;
typedef __attribute__((ext_vector_type(4))) float f32x4;

__device__ inline unsigned short f2bf(float x) {
    unsigned u = __float_as_uint(x);
    unsigned r = (u + 0x7FFFu + ((u >> 16) & 1u)) >> 16;   // RNE
    return (unsigned short)r;
}
__device__ inline float bf2f(unsigned short b) { return __uint_as_float(((unsigned)b) << 16); }
__device__ inline float bflo(unsigned u) { return __uint_as_float(u << 16); }
__device__ inline float bfhi(unsigned u) { return __uint_as_float(u & 0xFFFF0000u); }

__device__ inline void gload_lds16(const void* g, void* l) {
    __builtin_amdgcn_global_load_lds(
        (const __attribute__((address_space(1))) unsigned int*)g,
        (__attribute__((address_space(3))) unsigned int*)(unsigned long long)(uintptr_t)l,
        16, 0, 0);
}

// ============ CSR construction: LDS-binned bucket sort (rebuilt every call) ============
// entry pack: src (bits 0-16) | (dst & 1023) << 17

__global__ __launch_bounds__(256) void k_bucket2(const int* __restrict__ src,
                                                 const int* __restrict__ dst, int E, int nbuk,
                                                 int* __restrict__ bcur,
                                                 unsigned* __restrict__ ebuf) {
    __shared__ int bincnt[MAXBUK];
    __shared__ int binbase[MAXBUK];
    __shared__ unsigned binbuf[MAXBUK][BINCAP];
    const int t = threadIdx.x;
    for (int i = t; i < MAXBUK; i += 256) bincnt[i] = 0;
    __syncthreads();

    const int e0 = blockIdx.x * EPB;
#pragma unroll
    for (int q = 0; q < EPB / 256; q++) {
        int e = e0 + q * 256 + t;
        if (e < E) {
            int s = src[e], d = dst[e];
            int b = d >> BUKSH;
            unsigned v = (unsigned)s | ((unsigned)(d & ((1 << BUKSH) - 1)) << 17);
            int pos = atomicAdd(&bincnt[b], 1);
            if (pos < BINCAP) {
                binbuf[b][pos] = v;
            } else {
                int p = atomicAdd(&bcur[b], 1);
                if (p < BCAP2) ebuf[(size_t)b * BCAP2 + p] = v;
            }
        }
    }
    __syncthreads();

    if (t < MAXBUK) {
        int c = (t < nbuk) ? min(bincnt[t], BINCAP) : 0;
        binbase[t] = c ? atomicAdd(&bcur[t], c) : 0;
        bincnt[t] = c;
    }
    __syncthreads();

    const int wave = t >> 6, lane = t & 63;
    for (int b = wave; b < nbuk; b += 4) {
        int c = bincnt[b];
        int base = binbase[b];
        int cc = min(c, max(0, BCAP2 - base));
        for (int i = lane; i < cc; i += 64)
            ebuf[(size_t)b * BCAP2 + base + i] = binbuf[b][i];
    }
}

// Phase 1.5: per-bucket LDS histogram -> contiguous counts + dinv writes (fused).
__global__ __launch_bounds__(256) void k_hist2(const unsigned* __restrict__ ebuf,
                                               const int* __restrict__ bcur, int N,
                                               int* __restrict__ counts,
                                               float* __restrict__ dinv) {
    __shared__ int lcnt[1 << BUKSH];
    const int b = blockIdx.x, t = threadIdx.x;
    for (int i = t; i < (1 << BUKSH); i += 256) lcnt[i] = 0;
    __syncthreads();
    const int cnt = min(bcur[b], BCAP2);
    const unsigned* eb = ebuf + (size_t)b * BCAP2;
    for (int i = t; i < cnt; i += 256) atomicAdd(&lcnt[eb[i] >> 17], 1);
    __syncthreads();
    const int n0 = b << BUKSH;
    for (int i = t; i < (1 << BUKSH); i += 256)
        if (n0 + i < N) {
            int c = lcnt[i];
            counts[n0 + i] = c;
            dinv[n0 + i] = rsqrtf((float)(c + 1));
        }
}

__global__ void k_scan1(const int* __restrict__ counts, int N, int* __restrict__ offs,
                        int* __restrict__ bsums) {
    __shared__ int sm[1024];
    int i = blockIdx.x * 1024 + threadIdx.x;
    int v = (i < N) ? counts[i] : 0;
    sm[threadIdx.x] = v;
    __syncthreads();
    for (int d = 1; d < 1024; d <<= 1) {
        int t = (threadIdx.x >= d) ? sm[threadIdx.x - d] : 0;
        __syncthreads();
        sm[threadIdx.x] += t;
        __syncthreads();
    }
    if (i < N) offs[i] = sm[threadIdx.x] - v;
    if (threadIdx.x == 1023) bsums[blockIdx.x] = sm[1023];
}

__global__ void k_scan2(int* __restrict__ bsums, int nb) {
    __shared__ int sm[256];
    int x = threadIdx.x;
    int v = (x < nb) ? bsums[x] : 0;
    sm[x] = v;
    __syncthreads();
    for (int d = 1; d < 256; d <<= 1) {
        int t = (x >= d) ? sm[x - d] : 0;
        __syncthreads();
        sm[x] += t;
        __syncthreads();
    }
    if (x < nb) bsums[x] = sm[x] - v;
}

__global__ void k_scan3(int* __restrict__ offs, const int* __restrict__ bsums, int N, int E) {
    int i = blockIdx.x * 1024 + threadIdx.x;
    if (i < N) offs[i] += bsums[blockIdx.x];
    if (blockIdx.x == 0 && threadIdx.x == 0) offs[N] = E;
}

__global__ __launch_bounds__(256) void k_csr2(const unsigned* __restrict__ ebuf,
                                              const int* __restrict__ bcur,
                                              const int* __restrict__ offs, int N,
                                              int* __restrict__ ssrc) {
    __shared__ int lcur[1 << BUKSH];
    const int b = blockIdx.x, t = threadIdx.x;
    const int n0 = b << BUKSH;
    for (int i = t; i < (1 << BUKSH); i += 256)
        lcur[i] = (n0 + i < N) ? offs[n0 + i] : 0;
    __syncthreads();
    const int cnt = min(bcur[b], BCAP2);
    const unsigned* eb = ebuf + (size_t)b * BCAP2;
    for (int i = t; i < cnt; i += 256) {
        unsigned v = eb[i];
        int p = atomicAdd(&lcur[v >> 17], 1);
        ssrc[p] = (int)(v & 0x1FFFFu);
    }
}

// ---------------- W pack: per-kg contiguous MFMA B-fragment blocks (hi/lo interleaved) -------

__global__ void k_packW(const float* __restrict__ W, int K, int M,
                        unsigned short* __restrict__ wpk) {
    int idx = blockIdx.x * 256 + threadIdx.x;
    int total = K * M * 2;
    if (idx >= total) return;
    int j = idx & 7;
    int l = (idx >> 3) & 63;
    int h = (idx >> 9) & 1;
    int rest = idx >> 10;
    int NF = M >> 4;
    int f = rest % NF;
    int kg = rest / NF;
    int k = kg * 32 + (l >> 4) * 8 + j;
    int col = f * 16 + (l & 15);
    float v = W[(size_t)k * M + col];
    unsigned short hi = f2bf(v);
    wpk[idx] = h ? f2bf(v - bf2f(hi)) : hi;
}

// ------- layer-1 GEMM: C_bf16 = dinv ⊙ (A_f32[N,K] @ W[K,M]); 3-term split, LDS-staged B -----

template <int K, int M>
__global__ __launch_bounds__(256) void k_gemm1(const float* __restrict__ A,
                                               const unsigned short* __restrict__ wpk,
                                               const float* __restrict__ dinv,
                                               unsigned short* __restrict__ Cout, int N) {
    constexpr int NF = M / 16;
    constexpr int KG = K / 32;
    constexpr int KGB = NF * 2 * 1024;
    constexpr int NISS = KGB / 4096;
    __shared__ unsigned char smem[2][KGB];

    const int wave = threadIdx.x >> 6;
    const int lane = threadIdx.x & 63;
    const int c = lane & 15, g = lane >> 4;
    const int r0 = blockIdx.x * 128 + wave * 32;

    f32x4 acc[2][NF];
#pragma unroll
    for (int m = 0; m < 2; m++)
#pragma unroll
        for (int f = 0; f < NF; f++) acc[m][f] = (f32x4){0.f, 0.f, 0.f, 0.f};

    const int rA0 = min(r0 + c, N - 1);
    const int rA1 = min(r0 + 16 + c, N - 1);
    const float* ap0 = A + (size_t)rA0 * K + g * 8;
    const float* ap1 = A + (size_t)rA1 * K + g * 8;

#define STAGE1(kg_, buf_)                                                              \
    {                                                                                  \
        _Pragma("unroll") for (int i = 0; i < NISS; ++i) {                             \
            const unsigned short* gsrc =                                               \
                wpk + (((size_t)(kg_)*KGB + (size_t)i * 4096 + (size_t)wave * 1024) >> 1) + \
                (size_t)lane * 8;                                                      \
            gload_lds16(gsrc, &smem[buf_][i * 4096 + wave * 1024]);                    \
        }                                                                              \
    }

    STAGE1(0, 0);
    float av0[8], av1[8];
    *(float4*)&av0[0] = *(const float4*)(ap0);
    *(float4*)&av0[4] = *(const float4*)(ap0 + 4);
    *(float4*)&av1[0] = *(const float4*)(ap1);
    *(float4*)&av1[4] = *(const float4*)(ap1 + 4);
    __syncthreads();

    int buf = 0;
    for (int kg = 0; kg < KG; ++kg) {
        if (kg + 1 < KG) STAGE1(kg + 1, buf ^ 1);
        float nv0[8], nv1[8];
        if (kg + 1 < KG) {
            *(float4*)&nv0[0] = *(const float4*)(ap0 + (kg + 1) * 32);
            *(float4*)&nv0[4] = *(const float4*)(ap0 + (kg + 1) * 32 + 4);
            *(float4*)&nv1[0] = *(const float4*)(ap1 + (kg + 1) * 32);
            *(float4*)&nv1[4] = *(const float4*)(ap1 + (kg + 1) * 32 + 4);
        }
        bf16x8 ah0, al0, ah1, al1;
#pragma unroll
        for (int j = 0; j < 8; ++j) {
            unsigned short h0 = f2bf(av0[j]);
            unsigned short h1 = f2bf(av1[j]);
            ah0[j] = (short)h0;
            ah1[j] = (short)h1;
            al0[j] = (short)f2bf(av0[j] - bf2f(h0));
            al1[j] = (short)f2bf(av1[j] - bf2f(h1));
        }
#pragma unroll
        for (int f = 0; f < NF; ++f) {
            bf16x8 bh = *(const bf16x8*)&smem[buf][(f * 2 + 0) * 1024 + lane * 16];
            bf16x8 bl = *(const bf16x8*)&smem[buf][(f * 2 + 1) * 1024 + lane * 16];
            acc[0][f] = __builtin_amdgcn_mfma_f32_16x16x32_bf16(al0, bh, acc[0][f], 0, 0, 0);
            acc[0][f] = __builtin_amdgcn_mfma_f32_16x16x32_bf16(ah0, bl, acc[0][f], 0, 0, 0);
            acc[0][f] = __builtin_amdgcn_mfma_f32_16x16x32_bf16(ah0, bh, acc[0][f], 0, 0, 0);
            acc[1][f] = __builtin_amdgcn_mfma_f32_16x16x32_bf16(al1, bh, acc[1][f], 0, 0, 0);
            acc[1][f] = __builtin_amdgcn_mfma_f32_16x16x32_bf16(ah1, bl, acc[1][f], 0, 0, 0);
            acc[1][f] = __builtin_amdgcn_mfma_f32_16x16x32_bf16(ah1, bh, acc[1][f], 0, 0, 0);
        }
        if (kg + 1 < KG) {
#pragma unroll
            for (int j = 0; j < 8; ++j) { av0[j] = nv0[j]; av1[j] = nv1[j]; }
        }
        __syncthreads();
        buf ^= 1;
    }
#undef STAGE1

#pragma unroll
    for (int m = 0; m < 2; m++) {
#pragma unroll
        for (int reg = 0; reg < 4; reg++) {
            int row = r0 + m * 16 + g * 4 + reg;
            if (row < N) {
                float sc = dinv[row];
#pragma unroll
                for (int f = 0; f < NF; f++)
                    Cout[(size_t)row * M + f * 16 + c] = f2bf(acc[m][f][reg] * sc);
            }
        }
    }
}

// ------- layers 2-4 GEMM: C_bf16 = dinv ⊙ (A_bf16[N,K] @ W[K,M]); 2-term, LDS-staged B ------

template <int K, int M>
__global__ __launch_bounds__(256) void k_gemm_bf(const unsigned short* __restrict__ A,
                                                 const unsigned short* __restrict__ wpk,
                                                 const float* __restrict__ dinv,
                                                 unsigned short* __restrict__ Cout, int N) {
    constexpr int NF = M / 16;
    constexpr int KG = K / 32;
    constexpr int KGB = NF * 2 * 1024;
    constexpr int NISS = KGB / 4096;
    __shared__ unsigned char smem[2][KGB];

    const int wave = threadIdx.x >> 6;
    const int lane = threadIdx.x & 63;
    const int c = lane & 15, g = lane >> 4;
    const int r0 = blockIdx.x * 128 + wave * 32;

    f32x4 acc[2][NF];
#pragma unroll
    for (int m = 0; m < 2; m++)
#pragma unroll
        for (int f = 0; f < NF; f++) acc[m][f] = (f32x4){0.f, 0.f, 0.f, 0.f};

    const int rA0 = min(r0 + c, N - 1);
    const int rA1 = min(r0 + 16 + c, N - 1);
    const unsigned short* ap0 = A + (size_t)rA0 * K + g * 8;
    const unsigned short* ap1 = A + (size_t)rA1 * K + g * 8;

#define STAGE2(kg_, buf_)                                                              \
    {                                                                                  \
        _Pragma("unroll") for (int i = 0; i < NISS; ++i) {                             \
            const unsigned short* gsrc =                                               \
                wpk + (((size_t)(kg_)*KGB + (size_t)i * 4096 + (size_t)wave * 1024) >> 1) + \
                (size_t)lane * 8;                                                      \
            gload_lds16(gsrc, &smem[buf_][i * 4096 + wave * 1024]);                    \
        }                                                                              \
    }

    STAGE2(0, 0);
    bf16x8 af0[KG], af1[KG];
#pragma unroll
    for (int kg = 0; kg < KG; ++kg) {
        af0[kg] = *(const bf16x8*)(ap0 + kg * 32);
        af1[kg] = *(const bf16x8*)(ap1 + kg * 32);
    }
    __syncthreads();

    int buf = 0;
#pragma unroll
    for (int kg = 0; kg < KG; ++kg) {
        if (kg + 1 < KG) STAGE2(kg + 1, buf ^ 1);
#pragma unroll
        for (int f = 0; f < NF; ++f) {
            bf16x8 bh = *(const bf16x8*)&smem[buf][(f * 2 + 0) * 1024 + lane * 16];
            bf16x8 bl = *(const bf16x8*)&smem[buf][(f * 2 + 1) * 1024 + lane * 16];
            acc[0][f] = __builtin_amdgcn_mfma_f32_16x16x32_bf16(af0[kg], bl, acc[0][f], 0, 0, 0);
            acc[0][f] = __builtin_amdgcn_mfma_f32_16x16x32_bf16(af0[kg], bh, acc[0][f], 0, 0, 0);
            acc[1][f] = __builtin_amdgcn_mfma_f32_16x16x32_bf16(af1[kg], bl, acc[1][f], 0, 0, 0);
            acc[1][f] = __builtin_amdgcn_mfma_f32_16x16x32_bf16(af1[kg], bh, acc[1][f], 0, 0, 0);
        }
        __syncthreads();
        buf ^= 1;
    }
#undef STAGE2

#pragma unroll
    for (int m = 0; m < 2; m++) {
#pragma unroll
        for (int reg = 0; reg < 4; reg++) {
            int row = r0 + m * 16 + g * 4 + reg;
            if (row < N) {
                float sc = dinv[row];
#pragma unroll
                for (int f = 0; f < NF; f++)
                    Cout[(size_t)row * M + f * 16 + c] = f2bf(acc[m][f][reg] * sc);
            }
        }
    }
}

// ---- aggregate (M=128, bf16 rows in AND out): out = relu(dn*(g[n]+Σ g[src]) + b) ----

__global__ __launch_bounds__(256) void k_aggbf(const unsigned* __restrict__ g,
                                               const int* __restrict__ offs,
                                               const int* __restrict__ ssrc,
                                               const float* __restrict__ dinv,
                                               const float* __restrict__ bias,
                                               unsigned* __restrict__ out, int N) {
    int wid = (int)(((size_t)blockIdx.x * blockDim.x + threadIdx.x) >> 6);
    int lane = threadIdx.x & 63;
    if (wid >= N) return;
    const int n = wid;
    const float dn = dinv[n];
    unsigned u = g[(size_t)n * 64 + lane];
    float ax = bflo(u), ay = bfhi(u);
    const int e0 = offs[n], e1 = offs[n + 1];
    int j = e0;
    for (; j + 8 <= e1; j += 8) {
        int sv[8];
#pragma unroll
        for (int q = 0; q < 8; q++) sv[q] = ssrc[j + q];
        unsigned uv[8];
#pragma unroll
        for (int q = 0; q < 8; q++) uv[q] = g[(size_t)sv[q] * 64 + lane];
#pragma unroll
        for (int q = 0; q < 8; q++) { ax += bflo(uv[q]); ay += bfhi(uv[q]); }
    }
    if (j + 4 <= e1) {
        int sv[4];
#pragma unroll
        for (int q = 0; q < 4; q++) sv[q] = ssrc[j + q];
        unsigned uv[4];
#pragma unroll
        for (int q = 0; q < 4; q++) uv[q] = g[(size_t)sv[q] * 64 + lane];
#pragma unroll
        for (int q = 0; q < 4; q++) { ax += bflo(uv[q]); ay += bfhi(uv[q]); }
        j += 4;
    }
    for (; j < e1; ++j) {
        unsigned uu = g[(size_t)ssrc[j] * 64 + lane];
        ax += bflo(uu); ay += bfhi(uu);
    }
    float2 b = ((const float2*)bias)[lane];
    float ox = fmaxf(fmaf(dn, ax, b.x), 0.f);
    float oy = fmaxf(fmaf(dn, ay, b.y), 0.f);
    out[(size_t)n * 64 + lane] = ((unsigned)f2bf(oy) << 16) | (unsigned)f2bf(ox);
}

// ---------------- final aggregate (M=64, bf16 rows) + log_softmax, fp32 out ----------------

__global__ __launch_bounds__(256) void k_agg64f(const unsigned short* __restrict__ g,
                                                const int* __restrict__ offs,
                                                const int* __restrict__ ssrc,
                                                const float* __restrict__ dinv,
                                                const float* __restrict__ bias,
                                                float* __restrict__ out, int N) {
    int wid = (int)(((size_t)blockIdx.x * blockDim.x + threadIdx.x) >> 6);
    int lane = threadIdx.x & 63;
    if (wid >= N) return;
    const int n = wid;
    const float dn = dinv[n];
    float acc = bf2f(g[(size_t)n * 64 + lane]);
    const int e0 = offs[n], e1 = offs[n + 1];
    int j = e0;
    for (; j + 8 <= e1; j += 8) {
        int sv[8];
#pragma unroll
        for (int q = 0; q < 8; q++) sv[q] = ssrc[j + q];
        float fv[8];
#pragma unroll
        for (int q = 0; q < 8; q++) fv[q] = bf2f(g[(size_t)sv[q] * 64 + lane]);
#pragma unroll
        for (int q = 0; q < 8; q++) acc += fv[q];
    }
    for (; j < e1; ++j) acc += bf2f(g[(size_t)ssrc[j] * 64 + lane]);
    float v = fmaxf(fmaf(dn, acc, bias[lane]), 0.f);
    float m = v;
#pragma unroll
    for (int d = 1; d < 64; d <<= 1) m = fmaxf(m, __shfl_xor(m, d));
    float ex = expf(v - m);
    float ssum = ex;
#pragma unroll
    for (int d = 1; d < 64; d <<= 1) ssum += __shfl_xor(ssum, d);
    out[(size_t)n * 64 + lane] = v - m - logf(ssum);
}

// ---------------- launcher ----------------

extern "C" void kernel_launch(void* const* d_in, const int* in_sizes, int n_in,
                              void* d_out, int out_size, void* d_ws, size_t ws_size,
                              hipStream_t stream) {
    const float* x  = (const float*)d_in[0];
    const int*   ei = (const int*)d_in[1];
    const float* W1 = (const float*)d_in[2];
    const float* b1 = (const float*)d_in[3];
    const float* W2 = (const float*)d_in[4];
    const float* b2 = (const float*)d_in[5];
    const float* W3 = (const float*)d_in[6];
    const float* b3 = (const float*)d_in[7];
    const float* W4 = (const float*)d_in[8];
    const float* b4 = (const float*)d_in[9];

    const int N = in_sizes[0] / IN_DIM;     // 100000
    const int E = in_sizes[1] / 2;          // 1600000
    const int nbuk = (N + (1 << BUKSH) - 1) >> BUKSH;   // 98
    const int* src = ei;
    const int* dst = ei + E;

    char* p = (char*)d_ws;
    unsigned short* hbf = (unsigned short*)p; p += (size_t)N * HID * 2;     // gemm out (bf16)
    unsigned short* abf = (unsigned short*)p; p += (size_t)N * HID * 2;     // agg out (bf16)
    unsigned short* h4  = (unsigned short*)p; p += (size_t)N * OUT_DIM * 2; // gemm4 out (bf16)
    float* dinv = (float*)p;          p += (size_t)N * sizeof(float);
    int* counts = (int*)p;            p += (size_t)N * sizeof(int);
    int* bcur   = (int*)p;            p += (size_t)nbuk * sizeof(int);
    int* offs   = (int*)p;            p += (size_t)(N + 1) * sizeof(int);
    int* bsums  = (int*)p;            p += 256 * sizeof(int);
    int* ssrc   = (int*)p;            p += (size_t)E * sizeof(int);
    unsigned* ebuf = (unsigned*)p;    p += (size_t)nbuk * BCAP2 * sizeof(unsigned);
    unsigned short* w1p = (unsigned short*)p; p += (size_t)IN_DIM * HID * 2 * 2;
    unsigned short* w2p = (unsigned short*)p; p += (size_t)HID * HID * 2 * 2;
    unsigned short* w3p = (unsigned short*)p; p += (size_t)HID * HID * 2 * 2;
    unsigned short* w4p = (unsigned short*)p; p += (size_t)HID * OUT_DIM * 2 * 2;

    (void)hipMemsetAsync(bcur, 0, (size_t)nbuk * sizeof(int), stream);

    const int nb = (N + 1023) / 1024;
    const int nchunks = (E + EPB - 1) / EPB;
    k_bucket2<<<nchunks, 256, 0, stream>>>(src, dst, E, nbuk, bcur, ebuf);
    k_hist2<<<nbuk, 256, 0, stream>>>(ebuf, bcur, N, counts, dinv);
    k_scan1<<<nb, 1024, 0, stream>>>(counts, N, offs, bsums);
    k_scan2<<<1, 256, 0, stream>>>(bsums, nb);
    k_scan3<<<nb, 1024, 0, stream>>>(offs, bsums, N, E);
    k_csr2<<<nbuk, 256, 0, stream>>>(ebuf, bcur, offs, N, ssrc);

    k_packW<<<(IN_DIM * HID * 2 + 255) / 256, 256, 0, stream>>>(W1, IN_DIM, HID, w1p);
    k_packW<<<(HID * HID * 2 + 255) / 256, 256, 0, stream>>>(W2, HID, HID, w2p);
    k_packW<<<(HID * HID * 2 + 255) / 256, 256, 0, stream>>>(W3, HID, HID, w3p);
    k_packW<<<(HID * OUT_DIM * 2 + 255) / 256, 256, 0, stream>>>(W4, HID, OUT_DIM, w4p);

    const int gb = (N + 127) / 128;    // 128 rows / block (32 per wave)
    const int ab = (N + 3) / 4;
    k_gemm1<IN_DIM, HID><<<gb, 256, 0, stream>>>(x, w1p, dinv, hbf, N);
    k_aggbf<<<ab, 256, 0, stream>>>((const unsigned*)hbf, offs, ssrc, dinv, b1, (unsigned*)abf, N);
    k_gemm_bf<HID, HID><<<gb, 256, 0, stream>>>(abf, w2p, dinv, hbf, N);
    k_aggbf<<<ab, 256, 0, stream>>>((const unsigned*)hbf, offs, ssrc, dinv, b2, (unsigned*)abf, N);
    k_gemm_bf<HID, HID><<<gb, 256, 0, stream>>>(abf, w3p, dinv, hbf, N);
    k_aggbf<<<ab, 256, 0, stream>>>((const unsigned*)hbf, offs, ssrc, dinv, b3, (unsigned*)abf, N);
    k_gemm_bf<HID, OUT_DIM><<<gb, 256, 0, stream>>>(abf, w4p, dinv, h4, N);
    k_agg64f<<<ab, 256, 0, stream>>>(h4, offs, ssrc, dinv, b4, (float*)d_out, N);
}